// Round 3
// baseline (349.273 us; speedup 1.0000x reference)
//
#include <hip/hip_runtime.h>

// CRF forward: T=512 (serial scan), B=2048, K=32.
// lane = (b, i); 2 batch items per wave64; 1024 waves total.
// Internal log domain is base-2 (score2 = score_nat * log2(e)).

#define T_LEN 512
#define B_SZ  2048
#define K_SZ  32
#define TBK   (B_SZ * K_SZ)   // 65536 floats per timestep of hiddens
#define START_S (K_SZ - 3)
#define END_S   (K_SZ - 2)
#define LOG2E_F 1.4426950408889634f
#define LN2_F   0.6931471805599453f

#if defined(__has_builtin)
#if __has_builtin(__builtin_amdgcn_exp2f)
#define EXP2F(x) __builtin_amdgcn_exp2f(x)
#else
#define EXP2F(x) exp2f(x)
#endif
#if __has_builtin(__builtin_amdgcn_logf)
#define LOG2F(x) __builtin_amdgcn_logf(x)
#else
#define LOG2F(x) log2f(x)
#endif
#else
#define EXP2F(x) exp2f(x)
#define LOG2F(x) log2f(x)
#endif

__device__ __forceinline__ float grp32_max(float v) {
  v = fmaxf(v, __shfl_xor(v, 1));
  v = fmaxf(v, __shfl_xor(v, 2));
  v = fmaxf(v, __shfl_xor(v, 4));
  v = fmaxf(v, __shfl_xor(v, 8));
  v = fmaxf(v, __shfl_xor(v, 16));
  return v;
}

// One CRF step for this lane's (b, i). ebuf = this group's 32-float LDS row.
// Returns the un-masked new score (base-2 units).
__device__ __forceinline__ float crf_step(float score, float h, float* ebuf,
                                          int lane, const float (&et)[K_SZ]) {
  float M = grp32_max(score);
  float e = EXP2F(score - M);                    // <= 1, exact-max normalized
  ebuf[lane] = e;                                 // wave-private LDS, in-order DS pipe
  float s0 = 0.f, s1 = 0.f, s2 = 0.f, s3 = 0.f;
  #pragma unroll
  for (int q = 0; q < 8; ++q) {
    float4 eq = *(const float4*)&ebuf[q * 4];     // broadcast read, conflict-free
    s0 = fmaf(eq.x, et[q * 4 + 0], s0);
    s1 = fmaf(eq.y, et[q * 4 + 1], s1);
    s2 = fmaf(eq.z, et[q * 4 + 2], s2);
    s3 = fmaf(eq.w, et[q * 4 + 3], s3);
  }
  float sum = (s0 + s1) + (s2 + s3);
  // sum == 0 for rows whose exp(trans) row is all zero (START) -> clamp finite.
  float lg = (sum > 0.f) ? LOG2F(sum) : -25000.0f;  // v_log_f32 = log2
  return fmaf(h, LOG2E_F, M + lg);
}

__global__ __launch_bounds__(256, 1) void crf_fwd_kernel(
    const float* __restrict__ hid,    // (T, B, K)
    const float* __restrict__ msk,    // (T, B)
    const float* __restrict__ trans,  // (K, K)
    float* __restrict__ out)          // (B,)
{
  __shared__ float eb0[8][32];
  __shared__ float eb1[8][32];

  const int tx   = threadIdx.x;
  const int lane = tx & 31;           // state index i
  const int grp  = tx >> 5;           // group within block
  const int tid  = blockIdx.x * 256 + tx;
  const int b    = tid >> 5;          // batch index

  // Per-lane row i of exp(trans): et[j] = e^{trans[i][j]} = 2^{trans*log2e}.
  // NEG (-10000) entries underflow to exactly 0.
  float et[K_SZ];
  #pragma unroll
  for (int j = 0; j < K_SZ; ++j)
    et[j] = EXP2F(trans[lane * K_SZ + j] * LOG2E_F);
  const float t2e = trans[END_S * K_SZ + lane] * LOG2E_F;  // trans[END][i], base-2

  float score = (lane == START_S) ? 0.0f : (-10000.0f * LOG2E_F);

  const float* hp = hid + tid;   // hiddens[t][b][i] = hp[t*TBK]
  const float* mp = msk + b;     // masks[t][b]      = mp[t*B_SZ]

  // 8-deep prefetch ring for hiddens.
  float pre[8];
  #pragma unroll
  for (int k = 0; k < 8; ++k) pre[k] = hp[k * TBK];

  // ---- Phase 1: t in [0, 256). lengths >= 256 so mask == 0 always. ----
  for (int t0 = 0; t0 < 256; t0 += 8) {
    #pragma unroll
    for (int k = 0; k < 8; ++k) {
      float h = pre[k];
      pre[k] = hp[(t0 + 8 + k) * TBK];            // max t loaded = 263 < 512
      float* ebp = (k & 1) ? &eb1[grp][0] : &eb0[grp][0];
      score = crf_step(score, h, ebp, lane, et);
    }
  }

  // ---- Phase 2: t in [256, 512) with mask select. ----
  float mpre[8];
  #pragma unroll
  for (int k = 0; k < 8; ++k) mpre[k] = mp[(256 + k) * B_SZ];

  for (int t0 = 256; t0 < 512; t0 += 8) {
    #pragma unroll
    for (int k = 0; k < 8; ++k) {
      float h  = pre[k];
      float mv = mpre[k];
      int tn = t0 + 8 + k;
      tn = (tn < T_LEN) ? tn : (T_LEN - 1);       // clamp prefetch (harmless re-read)
      pre[k]  = hp[tn * TBK];
      mpre[k] = mp[tn * B_SZ];
      float* ebp = (k & 1) ? &eb1[grp][0] : &eb0[grp][0];
      float ns = crf_step(score, h, ebp, lane, et);
      score = (mv > 0.5f) ? score : ns;           // mask==1 -> keep old score
    }
  }

  // ---- Final: out[b] = LSE_i(score[i] + trans[END][i]) in nats. ----
  float v  = score + t2e;
  float Mv = grp32_max(v);
  float ex = EXP2F(v - Mv);
  float sm = ex;
  sm += __shfl_xor(sm, 1);
  sm += __shfl_xor(sm, 2);
  sm += __shfl_xor(sm, 4);
  sm += __shfl_xor(sm, 8);
  sm += __shfl_xor(sm, 16);
  if (lane == 0) out[b] = (Mv + LOG2F(sm)) * LN2_F;
}

extern "C" void kernel_launch(void* const* d_in, const int* in_sizes, int n_in,
                              void* d_out, int out_size, void* d_ws, size_t ws_size,
                              hipStream_t stream) {
  const float* hid   = (const float*)d_in[0];   // (512, 2048, 32) f32
  const float* msk   = (const float*)d_in[1];   // (512, 2048)     f32
  const float* trans = (const float*)d_in[2];   // (32, 32)        f32
  float* out = (float*)d_out;                   // (2048,)         f32

  crf_fwd_kernel<<<dim3(TBK / 256), dim3(256), 0, stream>>>(hid, msk, trans, out);
}

// Round 4
// 221.649 us; speedup vs baseline: 1.5758x; 1.5758x over previous
//
#include <hip/hip_runtime.h>

// CRF forward via forward-backward T-split, pure exp-domain scan.
// answer_b = ln2 * (Ra + Rb + log2( sum_j eA[b][j] * eB[b][j] ))
//   eA: forward scan t=0..255  (mask always 0 there since lengths >= 256)
//   eB: backward scan t=511..256 (all masking handled here; init = e^trans[END][:])
// Per-step recursion kept entirely in exp-domain:
//   fwd: e'_i = eh_i * sum_j et[i][j] * e_j
//   bwd: e'_j = sum_i et[i][j] * (e_i * eh_i)   (masked: e' = e)
// Renorm every 4 steps by exact power of 2 (shfl lane0 -> ilogb -> ldexp), R += s.

#define T_LEN 512
#define B_SZ  2048
#define K_SZ  32
#define TBK   (B_SZ * K_SZ)
#define HALF_T 256
#define START_S 29
#define END_S   30
#define L2E 1.4426950408889634f
#define LN2 0.6931471805599453f

#if defined(__has_builtin) && __has_builtin(__builtin_amdgcn_logf)
#define LOG2F(x) __builtin_amdgcn_logf(x)
#else
#define LOG2F(x) log2f(x)
#endif

__device__ __forceinline__ float matvec32(const float* eb, const float (&w)[K_SZ]) {
  float s0 = 0.f, s1 = 0.f, s2 = 0.f, s3 = 0.f;
  #pragma unroll
  for (int q = 0; q < 8; ++q) {
    float4 v = *(const float4*)&eb[q * 4];   // broadcast within 32-group: conflict-free
    s0 = fmaf(v.x, w[q * 4 + 0], s0);
    s1 = fmaf(v.y, w[q * 4 + 1], s1);
    s2 = fmaf(v.z, w[q * 4 + 2], s2);
    s3 = fmaf(v.w, w[q * 4 + 3], s3);
  }
  return (s0 + s1) + (s2 + s3);
}

__global__ __launch_bounds__(256, 2) void crf_scan(
    const float* __restrict__ hid, const float* __restrict__ msk,
    const float* __restrict__ trans,
    float* __restrict__ EA, float* __restrict__ RA,
    float* __restrict__ EB, float* __restrict__ RB)
{
  __shared__ float eb[8][2][32];

  const int tx   = threadIdx.x;
  const int lane = tx & 31;          // state index
  const int grp  = tx >> 5;
  const bool fwd = (blockIdx.x < 256);
  const int  bid = fwd ? blockIdx.x : (blockIdx.x - 256);
  const int  tid = bid * 256 + tx;
  const int  b   = tid >> 5;

  float R = 0.f;

  if (fwd) {
    // w[j] = e^{trans[lane][j]}  (NEG entries underflow to exact 0)
    float w[K_SZ];
    #pragma unroll
    for (int j = 0; j < K_SZ; ++j) w[j] = exp2f(trans[lane * K_SZ + j] * L2E);

    float e = (lane == START_S) ? 1.f : 0.f;
    const float* hp = hid + tid;

    float ehr[8];
    #pragma unroll
    for (int k = 0; k < 8; ++k) ehr[k] = exp2f(hp[k * TBK] * L2E);

    for (int t0 = 0; t0 < HALF_T; t0 += 8) {
      #pragma unroll
      for (int k = 0; k < 8; ++k) {
        float ehc = ehr[k];
        float hn  = hp[(t0 + 8 + k) * TBK];        // max t = 263 < 512: in-bounds
        eb[grp][k & 1][lane] = e;
        float sum = matvec32(&eb[grp][k & 1][0], w);
        ehr[k] = exp2f(hn * L2E);                  // off-chain, 8 steps ahead
        e = sum * ehc;
        if ((k & 3) == 3) {                        // exact pow2 renorm every 4 steps
          float c = __shfl(e, 0, 32);              // lane0 (state 0) > 0 always
          int   s = ilogbf(c);
          e = ldexpf(e, -s);
          R += (float)s;
        }
      }
    }
    EA[tid] = e;
    if (lane == 0) RA[b] = R;
  } else {
    // wT[i] = e^{trans[i][lane]}  (transposed access for backward recursion)
    float w[K_SZ];
    #pragma unroll
    for (int i = 0; i < K_SZ; ++i) w[i] = exp2f(trans[i * K_SZ + lane] * L2E);

    float e = exp2f(trans[END_S * K_SZ + lane] * L2E);  // beta init = e^{trans[END][:]}
    const float* hp = hid + (long)(T_LEN - 1) * TBK + tid;
    const float* mp = msk + (long)(T_LEN - 1) * B_SZ + b;

    float ehr[8], mr[8];
    #pragma unroll
    for (int k = 0; k < 8; ++k) {
      ehr[k] = exp2f(hp[-(long)k * TBK] * L2E);
      mr[k]  = mp[-(long)k * B_SZ];
    }

    for (int t0 = 0; t0 < HALF_T; t0 += 8) {
      #pragma unroll
      for (int k = 0; k < 8; ++k) {
        float ehc = ehr[k];
        float mv  = mr[k];
        long  nx  = t0 + 8 + k; nx = (nx <= HALF_T - 1) ? nx : (HALF_T - 1);  // clamp
        float hn  = hp[-nx * TBK];
        float mn  = mp[-nx * B_SZ];
        float f = e * ehc;                          // beta * e^{h_t}
        eb[grp][k & 1][lane] = f;
        float sum = matvec32(&eb[grp][k & 1][0], w);
        ehr[k] = exp2f(hn * L2E);
        mr[k]  = mn;
        e = (mv > 0.5f) ? e : sum;                  // mask==1: frozen at init
        if ((k & 3) == 3) {
          float c = __shfl(e, 0, 32);
          int   s = ilogbf(c);
          e = ldexpf(e, -s);
          R += (float)s;
        }
      }
    }
    EB[tid] = e;
    if (lane == 0) RB[b] = R;
  }
}

__global__ __launch_bounds__(256) void crf_combine(
    const float* __restrict__ EA, const float* __restrict__ RA,
    const float* __restrict__ EB, const float* __restrict__ RB,
    float* __restrict__ out)
{
  const int tid  = blockIdx.x * 256 + threadIdx.x;
  const int lane = tid & 31;
  const int b    = tid >> 5;

  // Robust log-domain combine (handles exact zeros -> -inf -> exp2 -> 0).
  float la = LOG2F(EA[tid]);
  float lb = LOG2F(EB[tid]);
  float v  = la + lb;
  float M  = v;
  M = fmaxf(M, __shfl_xor(M, 1));
  M = fmaxf(M, __shfl_xor(M, 2));
  M = fmaxf(M, __shfl_xor(M, 4));
  M = fmaxf(M, __shfl_xor(M, 8));
  M = fmaxf(M, __shfl_xor(M, 16));
  float x = exp2f(v - M);
  x += __shfl_xor(x, 1);
  x += __shfl_xor(x, 2);
  x += __shfl_xor(x, 4);
  x += __shfl_xor(x, 8);
  x += __shfl_xor(x, 16);
  if (lane == 0) out[b] = (RA[b] + RB[b] + M + LOG2F(x)) * LN2;
}

extern "C" void kernel_launch(void* const* d_in, const int* in_sizes, int n_in,
                              void* d_out, int out_size, void* d_ws, size_t ws_size,
                              hipStream_t stream) {
  const float* hid   = (const float*)d_in[0];   // (512, 2048, 32) f32
  const float* msk   = (const float*)d_in[1];   // (512, 2048)     f32
  const float* trans = (const float*)d_in[2];   // (32, 32)        f32
  float* out = (float*)d_out;                   // (2048,)         f32

  // Workspace: EA[65536], RA[2048], EB[65536], RB[2048] = 540 KB.
  float* W  = (float*)d_ws;
  float* EA = W;
  float* RA = W + TBK;
  float* EB = W + TBK + B_SZ;
  float* RB = W + TBK + B_SZ + TBK;

  crf_scan<<<dim3(512), dim3(256), 0, stream>>>(hid, msk, trans, EA, RA, EB, RB);
  crf_combine<<<dim3(TBK / 256), dim3(256), 0, stream>>>(EA, RA, EB, RB, out);
}